// Round 6
// baseline (374.100 us; speedup 1.0000x reference)
//
#include <hip/hip_runtime.h>
#include <math.h>

// ---------------------------------------------------------------------------
// TransformerBlock: B=2, T=2048, D=1024, H=16, HD=64, pre-LN, causal attn, GELU
// Round 11 (base = round 10, 354.2us): W1 and W2 (the two 34.4-GFLOP FFN
// GEMMs) move to a 256x256-tile, BK=64, 8-wave, 8-phase deep-pipelined kernel
// (gemm256) per the verified m196->m201 ladder. Per K-tile: 4 phases of
// {ds_read subtile -> barrier -> lgkmcnt(0) -> sched_barrier -> setprio(1) ->
// 16 MFMA -> setprio(0) -> barrier}; half-tile prefetch at ph0/ph3 with
// counted vmcnt(4) once per tile (4 ops always in flight, no full drain).
// Chunk-XOR LDS swizzle (8 chunks/row for BK=64), pre-swizzled global source.
// W1: grid (16,16) = 256 blocks = 1/CU. W2: split-K=4, grid (16,4,4); z=0
// writes fp32 out(+bias+res), z=1..3 write f16 partials into dead workspace
// (W1^T / h16 / h2 regions); redux_kernel folds them. No atomics/memsets.
// QKV (MODE0), Wo (MODE1), attention: unchanged from round 10.
// ---------------------------------------------------------------------------

typedef _Float16 half8 __attribute__((ext_vector_type(8)));
typedef _Float16 half4v __attribute__((ext_vector_type(4)));
typedef float floatx4 __attribute__((ext_vector_type(4)));

#define DMODEL 1024
#define SEQT   2048
#define NTOK   4096   // B*T
#define NHEAD  16
#define HDIM   64

// Async global->LDS, 16B/lane. LDS dest = wave-uniform base + lane*16 [m104].
__device__ __forceinline__ void llds16(const _Float16* g, _Float16* l) {
  __builtin_amdgcn_global_load_lds(
      (const __attribute__((address_space(1))) void*)g,
      (__attribute__((address_space(3))) void*)l, 16, 0, 0);
}

// ---------------------------------------------------------------------------
// Weight convert+transpose: fp32 [K,N] -> f16 [N,K].
// wt layout (elements): Wq^T @0, Wk^T @1M, Wv^T @2M, Wo^T @3M, W1^T @4M (4096x1024),
//                       W2^T @8M (1024x4096). Total 12M halves = 24MB.
// ---------------------------------------------------------------------------
__global__ __launch_bounds__(256) void wtrans_kernel(
    const float* __restrict__ Wq, const float* __restrict__ Wk,
    const float* __restrict__ Wv, const float* __restrict__ Wo,
    const float* __restrict__ W1, const float* __restrict__ W2,
    _Float16* __restrict__ wt_base) {
  __shared__ float tilebuf[32][33];
  int id = blockIdx.x;
  const float* src; _Float16* dst; int K, N, t;
  if (id < 4096) {
    int s = id >> 10;
    src = (s == 0) ? Wq : (s == 1) ? Wk : (s == 2) ? Wv : Wo;
    dst = wt_base + (size_t)s * (1024 * 1024);
    K = 1024; N = 1024; t = id & 1023;
  } else if (id < 8192) {
    src = W1; dst = wt_base + (size_t)4 * 1024 * 1024; K = 1024; N = 4096; t = id - 4096;
  } else {
    src = W2; dst = wt_base + (size_t)8 * 1024 * 1024; K = 4096; N = 1024; t = id - 8192;
  }
  int tilesN = N >> 5;
  int tk = t / tilesN, tn = t % tilesN;
  int c = threadIdx.x & 31, r0 = threadIdx.x >> 5;
#pragma unroll
  for (int i = 0; i < 4; ++i) {
    int r = r0 + i * 8;
    tilebuf[r][c] = src[(size_t)(tk * 32 + r) * N + tn * 32 + c];
  }
  __syncthreads();
#pragma unroll
  for (int i = 0; i < 4; ++i) {
    int r = r0 + i * 8;
    dst[(size_t)(tn * 32 + r) * K + tk * 32 + c] = (_Float16)tilebuf[c][r];
  }
}

// ---------------------------------------------------------------------------
// LayerNorm: fp32 in -> f16 out. One row (D=1024) per 256-thread block.
// ---------------------------------------------------------------------------
__global__ __launch_bounds__(256) void ln_kernel(
    const float* __restrict__ x, const float* __restrict__ g,
    const float* __restrict__ b, _Float16* __restrict__ out) {
  int row = blockIdx.x;
  int t = threadIdx.x;
  const float4 xv = ((const float4*)(x + (size_t)row * DMODEL))[t];
  float s = xv.x + xv.y + xv.z + xv.w;
  float s2 = xv.x * xv.x + xv.y * xv.y + xv.z * xv.z + xv.w * xv.w;
#pragma unroll
  for (int off = 32; off; off >>= 1) {
    s += __shfl_down(s, off);
    s2 += __shfl_down(s2, off);
  }
  __shared__ float red[8];
  int wid = t >> 6;
  if ((t & 63) == 0) { red[wid] = s; red[wid + 4] = s2; }
  __syncthreads();
  s = red[0] + red[1] + red[2] + red[3];
  s2 = red[4] + red[5] + red[6] + red[7];
  float mu = s * (1.0f / DMODEL);
  float var = s2 * (1.0f / DMODEL) - mu * mu;
  float rstd = rsqrtf(var + 1e-5f);
  const float4 gv = ((const float4*)g)[t];
  const float4 bv = ((const float4*)b)[t];
  half4v o;
  o[0] = (_Float16)((xv.x - mu) * rstd * gv.x + bv.x);
  o[1] = (_Float16)((xv.y - mu) * rstd * gv.y + bv.y);
  o[2] = (_Float16)((xv.z - mu) * rstd * gv.z + bv.z);
  o[3] = (_Float16)((xv.w - mu) * rstd * gv.w + bv.w);
  *(half4v*)(out + (size_t)row * DMODEL + t * 4) = o;
}

// ---------------------------------------------------------------------------
// gemm256: C[4096, N] = A[4096,K] @ B (Bt[N,K] f16), 256x256 tile, BK=64,
// 512 threads (8 waves, 2M x 4N; wave tile 128x64), 8-phase schedule.
// LDS 128 KB: As/Bs [2][256*64] f16, 1 block/CU.
// Swizzle: row = 64 f16 = 8 chunks of 16B; chunk slot = c ^ (row&7).
// Staging pre-swizzles the GLOBAL source chunk (LDS dest linear, m104 rule);
// fragment reads apply the same XOR -> 16-lane groups hit 8 distinct 16B
// slots (2 lanes/bank = free, m136).
// Pipeline per K-tile kt (buf = kt&1): 4 phases, each computes one 64x32
// C-quadrant over K=64 (16 MFMA). Half-tile (4 ops/thread) prefetch: h1 of
// kt+1 at ph0, h0 of kt+2 at ph3 (after the all-read barrier). vmcnt(4) once
// per tile -> 4 ops always in flight. FIFO walk verified in comments below.
// OUTMODE 0: GELU -> f16 out, row stride 4096 (W1).
// OUTMODE 1: split-K over gridDim.z=4 (K-slice via koff); z==0 stores fp32
//            acc+bias+res to outf; z=1..3 store f16 partials to pz[z-1].
// ---------------------------------------------------------------------------
template <int OUTMODE>
__global__ __launch_bounds__(512, 2) void gemm256_kernel(
    const _Float16* __restrict__ A, const _Float16* __restrict__ Bt, int K,
    const float* __restrict__ bias, const float* __restrict__ res,
    float* __restrict__ outf, _Float16* __restrict__ outh,
    _Float16* __restrict__ p1, _Float16* __restrict__ p2,
    _Float16* __restrict__ p3) {
  __shared__ __align__(16) _Float16 As[2][256 * 64];
  __shared__ __align__(16) _Float16 Bs[2][256 * 64];
  const int tid = threadIdx.x;
  const int w = tid >> 6, lane = tid & 63;
  const int l15 = lane & 15, q8 = lane >> 4;
  const int wr = w >> 2, wc = w & 3;       // wave tile: rows wr*128, cols wc*64
  const int m0 = blockIdx.x * 256;
  const int n0 = blockIdx.y * 256;
  int Keff = K, koff = 0;
  if (OUTMODE == 1) { Keff = K >> 2; koff = blockIdx.z * Keff; }
  const int nk = Keff >> 6;  // 64-wide K-tiles (16 for both W1 and W2 slices)

  // Stage half-tile h (rows [h*128,+128) of A and Bt) of K-tile kt into buf.
  // 4 ops/thread (2 A + 2 B). LDS dest linear; global source chunk-swizzled.
  auto stage_half = [&](int kt, int buf, int h) {
#pragma unroll
    for (int o = 0; o < 2; ++o) {
      int cl = o * 512 + tid;          // chunk index within half (0..1023)
      int rr = cl >> 3;                // row within half
      int m = h * 128 + rr;            // row within tile
      int sc = (cl & 7) ^ (m & 7);     // pre-swizzled source chunk
      llds16(A + (size_t)(m0 + m) * K + koff + kt * 64 + sc * 8,
             &As[buf][h * 8192 + cl * 8]);
    }
#pragma unroll
    for (int o = 0; o < 2; ++o) {
      int cl = o * 512 + tid;
      int rr = cl >> 3;
      int m = h * 128 + rr;
      int sc = (cl & 7) ^ (m & 7);
      llds16(Bt + (size_t)(n0 + m) * K + koff + kt * 64 + sc * 8,
             &Bs[buf][h * 8192 + cl * 8]);
    }
  };

  floatx4 acc[8][4];
#pragma unroll
  for (int i = 0; i < 8; ++i)
#pragma unroll
    for (int j = 0; j < 4; ++j) acc[i][j] = (floatx4){0.f, 0.f, 0.f, 0.f};

  half8 a[4][2], b[2][2];

// A-frags for row-quadrant R2 (rows wr*128+R2*64 .. +63), both K-halves.
#define DSA(BUF, R2)                                                         \
  {                                                                          \
    _Pragma("unroll") for (int i = 0; i < 4; ++i) {                          \
      int rA = wr * 128 + (R2)*64 + i * 16 + l15;                            \
      _Pragma("unroll") for (int kh = 0; kh < 2; ++kh) {                     \
        int slot = (kh * 4 + q8) ^ (rA & 7);                                 \
        a[i][kh] = *(const half8*)&As[BUF][rA * 64 + slot * 8];              \
      }                                                                      \
    }                                                                        \
  }
// B-frags for col-quadrant (C2): cols wc*64+C2*32 .. +31.
#define DSB(BUF, C2)                                                         \
  {                                                                          \
    _Pragma("unroll") for (int j = 0; j < 2; ++j) {                          \
      int rB = wc * 64 + (C2)*32 + j * 16 + l15;                             \
      _Pragma("unroll") for (int kh = 0; kh < 2; ++kh) {                     \
        int slot = (kh * 4 + q8) ^ (rB & 7);                                 \
        b[j][kh] = *(const half8*)&Bs[BUF][rB * 64 + slot * 8];              \
      }                                                                      \
    }                                                                        \
  }
// 16 MFMA: quadrant (R2,C2) x K=64. Static acc indices (rule #20).
#define MFMAQ(R2, C2)                                                        \
  {                                                                          \
    _Pragma("unroll") for (int i = 0; i < 4; ++i)                            \
        _Pragma("unroll") for (int j = 0; j < 2; ++j)                        \
            _Pragma("unroll") for (int kh = 0; kh < 2; ++kh)                 \
                acc[(R2)*4 + i][(C2)*2 + j] =                                \
        __builtin_amdgcn_mfma_f32_16x16x32_f16(a[i][kh], b[j][kh],           \
                                               acc[(R2)*4 + i][(C2)*2 + j], \
                                               0, 0, 0);                     \
  }
#define PH_SYNC()                                           \
  __builtin_amdgcn_s_barrier();                             \
  asm volatile("s_waitcnt lgkmcnt(0)" ::: "memory");        \
  __builtin_amdgcn_sched_barrier(0);                        \
  __builtin_amdgcn_s_setprio(1);
#define PH_END()                                            \
  __builtin_amdgcn_s_setprio(0);                            \
  __builtin_amdgcn_s_barrier();

  // Prologue: tile 0 fully (8 ops), tile 1 half 0 (4 ops) -> vmcnt(4).
  stage_half(0, 0, 0);
  stage_half(0, 0, 1);
  if (nk > 1) {
    stage_half(1, 1, 0);
    asm volatile("s_waitcnt vmcnt(4)" ::: "memory");
  } else {
    asm volatile("s_waitcnt vmcnt(0)" ::: "memory");
  }
  __builtin_amdgcn_s_barrier();

  // In-flight FIFO at each loop top: {kt+1 h0} (4 ops).
  for (int kt = 0; kt < nk; ++kt) {
    const int buf = kt & 1;
    // ---- phase 0: quadrant (0,0); issue kt+1 h1 ----
    DSA(buf, 0);
    DSB(buf, 0);
    if (kt + 1 < nk) stage_half(kt + 1, buf ^ 1, 1);  // in flight: 8
    PH_SYNC();
    MFMAQ(0, 0);
    PH_END();
    // ---- phase 1: quadrant (0,1) (A regs reused) ----
    DSB(buf, 1);
    PH_SYNC();
    MFMAQ(0, 1);
    PH_END();
    // ---- phase 2: quadrant (1,0) ----
    DSA(buf, 1);
    DSB(buf, 0);
    PH_SYNC();
    MFMAQ(1, 0);
    PH_END();
    // ---- phase 3: quadrant (1,1); tile-boundary rendezvous ----
    DSB(buf, 1);
    PH_SYNC();
    MFMAQ(1, 1);
    __builtin_amdgcn_s_setprio(0);
    __builtin_amdgcn_s_barrier();  // all waves done reading buf (tile kt)
    if (kt + 2 < nk) stage_half(kt + 2, buf, 0);  // in flight: 12
    if (kt + 1 < nk) {
      // retire the 8 oldest = kt+1 h0+h1; keep kt+2 h0 (4) in flight
      asm volatile("s_waitcnt vmcnt(4)" ::: "memory");
    } else {
      asm volatile("s_waitcnt vmcnt(0)" ::: "memory");
    }
    __builtin_amdgcn_s_barrier();  // buf^1 (tile kt+1) ready for all waves
  }
#undef DSA
#undef DSB
#undef MFMAQ
#undef PH_SYNC
#undef PH_END

  // Epilogue. C/D layout: col = lane&15, row = (lane>>4)*4 + reg  [m89/m91]
#pragma unroll
  for (int fi = 0; fi < 8; ++fi) {
    int rowb = m0 + wr * 128 + fi * 16 + q8 * 4;
#pragma unroll
    for (int fj = 0; fj < 4; ++fj) {
      int col = n0 + wc * 64 + fj * 16 + l15;
      float bval = bias[col];
#pragma unroll
      for (int r = 0; r < 4; ++r) {
        int row = rowb + r;
        float v = acc[fi][fj][r];
        if (OUTMODE == 0) {
          v += bval;
          // fast GELU: v*sigmoid(1.5957691(v + 0.044715 v^3)); |err| < 0.003
          float z = 1.5957691216f * v * (1.0f + 0.044715f * v * v);
          float gl = v / (1.0f + __expf(-z));
          outh[(size_t)row * 4096 + col] = (_Float16)gl;
        } else {
          if (blockIdx.z == 0) {
            v += bval + res[(size_t)row * 1024 + col];
            outf[(size_t)row * 1024 + col] = v;
          } else {
            _Float16* pp = (blockIdx.z == 1) ? p1 : (blockIdx.z == 2) ? p2 : p3;
            pp[(size_t)row * 1024 + col] = (_Float16)v;
          }
        }
      }
    }
  }
}

// ---------------------------------------------------------------------------
// Split-K reduce: out += p1 + p2 + p3 (f16 partials). 4 floats/thread.
// ---------------------------------------------------------------------------
__global__ __launch_bounds__(256) void redux_kernel(
    float* __restrict__ out, const _Float16* __restrict__ p1,
    const _Float16* __restrict__ p2, const _Float16* __restrict__ p3) {
  size_t i = ((size_t)blockIdx.x * 256 + threadIdx.x) * 4;
  float4 o = *(float4*)(out + i);
  half4v a = *(const half4v*)(p1 + i);
  half4v b = *(const half4v*)(p2 + i);
  half4v c = *(const half4v*)(p3 + i);
  o.x += (float)a[0] + (float)b[0] + (float)c[0];
  o.y += (float)a[1] + (float)b[1] + (float)c[1];
  o.z += (float)a[2] + (float)b[2] + (float)c[2];
  o.w += (float)a[3] + (float)b[3] + (float)c[3];
  *(float4*)(out + i) = o;
}

// ---------------------------------------------------------------------------
// f16 MFMA GEMM (legacy path, QKV + Wo): tiles 128x128 (MODE 0) / 128x64
// (MODE 1), K-tile 32, double-buffered LDS + swizzle. Unchanged from r10
// except MODE1 reverts to the r9 __syncthreads loop (r10 4-buf was neutral).
// MODE 0: QKV fused; q,k scatter [B,H,T,HD]; v scatters TRANSPOSED [B,H,HD,T]
// MODE 1: bias + residual(fp32) add; fp32 output, row stride 1024
// ---------------------------------------------------------------------------
template <int MODE>
__global__ __launch_bounds__(256) void gemm_kernel(
    const _Float16* __restrict__ A, const _Float16* __restrict__ Bt0, int K,
    const float* __restrict__ bias0, const float* __restrict__ bias1,
    const float* __restrict__ bias2, const float* __restrict__ res,
    float* __restrict__ outf, _Float16* __restrict__ outh) {
  constexpr int NT = (MODE == 1) ? 64 : 128;   // N-tile
  constexpr int MI = (NT == 128) ? 4 : 2;      // A-frag rows per wave
  constexpr int BCH = NT / 64;                 // B staging chunks per thread
  __shared__ __align__(16) _Float16 As[2][128 * 32];
  __shared__ __align__(16) _Float16 Bs[2][NT * 32];
  const int tid = threadIdx.x;
  const int m0 = blockIdx.x * 128;
  const _Float16* Bt;
  const float* bias;
  _Float16* outh_sel = outh;
  int n0, sel = 0;
  if (MODE == 0) {
    sel = blockIdx.y >> 3;
    n0 = (blockIdx.y & 7) * 128;
    Bt = Bt0 + (size_t)sel * (1024 * 1024);
    bias = (sel == 0) ? bias0 : (sel == 1) ? bias1 : bias2;
    outh_sel = outh + (size_t)sel * ((size_t)NTOK * DMODEL);
  } else {
    n0 = blockIdx.y * NT;
    Bt = Bt0;
    bias = bias0;
  }
  const int w = tid >> 6, lane = tid & 63;
  const int l15 = lane & 15, q8 = lane >> 4;
  const int wrow = (NT == 128) ? (w >> 1) * 64 : w * 32;
  const int wcol = (NT == 128) ? (w & 1) * 64 : 0;
  const int csw = (q8 ^ ((l15 >> 1) & 3)) * 8;

  const _Float16* gA[2]; int ldsA[2];
  const _Float16* gB[BCH]; int ldsB[BCH];
#pragma unroll
  for (int i = 0; i < 2; ++i) {
    int c0 = i * 256 + w * 64;
    int idx = c0 + lane;
    int m = idx >> 2;
    int kq = ((idx & 3) ^ ((m >> 1) & 3)) * 8;
    gA[i] = A + (size_t)(m0 + m) * K + kq;
    ldsA[i] = c0 * 8;
  }
#pragma unroll
  for (int i = 0; i < BCH; ++i) {
    int c0 = i * 256 + w * 64;
    int idx = c0 + lane;
    int m = idx >> 2;
    int kq = ((idx & 3) ^ ((m >> 1) & 3)) * 8;
    gB[i] = Bt + (size_t)(n0 + m) * K + kq;
    ldsB[i] = c0 * 8;
  }

  auto stage = [&](int buf) {
#pragma unroll
    for (int i = 0; i < 2; ++i) {
      llds16(gA[i], &As[buf][ldsA[i]]);
      gA[i] += 32;
    }
#pragma unroll
    for (int i = 0; i < BCH; ++i) {
      llds16(gB[i], &Bs[buf][ldsB[i]]);
      gB[i] += 32;
    }
  };

  floatx4 acc[MI][4];
#pragma unroll
  for (int i = 0; i < MI; ++i)
#pragma unroll
    for (int j = 0; j < 4; ++j) acc[i][j] = (floatx4){0.f, 0.f, 0.f, 0.f};

  const int nk = K >> 5;
  stage(0);
  __syncthreads();
  for (int t = 0; t < nk; ++t) {
    const int buf = t & 1;
    if (t + 1 < nk) stage(buf ^ 1);
    half8 af[MI], bf[4];
#pragma unroll
    for (int i = 0; i < MI; ++i)
      af[i] = *(const half8*)&As[buf][(wrow + i * 16 + l15) * 32 + csw];
#pragma unroll
    for (int j = 0; j < 4; ++j)
      bf[j] = *(const half8*)&Bs[buf][(wcol + j * 16 + l15) * 32 + csw];
#pragma unroll
    for (int i = 0; i < MI; ++i)
#pragma unroll
      for (int j = 0; j < 4; ++j)
        acc[i][j] = __builtin_amdgcn_mfma_f32_16x16x32_f16(af[i], bf[j], acc[i][j], 0, 0, 0);
    __syncthreads();
  }

#pragma unroll
  for (int i = 0; i < MI; ++i) {
    int rowb = m0 + wrow + i * 16 + q8 * 4;
#pragma unroll
    for (int j = 0; j < 4; ++j) {
      int col = n0 + wcol + j * 16 + l15;
      float bval = bias[col];
#pragma unroll
      for (int r = 0; r < 4; ++r) {
        int row = rowb + r;
        float v = acc[i][j][r] + bval;
        if (MODE == 0) {
          int bb = row >> 11, tt = row & 2047;
          int hh = col >> 6, hd = col & 63;
          if (sel == 2)
            outh_sel[((size_t)(bb * NHEAD + hh) * HDIM + hd) * SEQT + tt] = (_Float16)v;
          else
            outh_sel[((size_t)(bb * NHEAD + hh) * SEQT + tt) * HDIM + hd] = (_Float16)v;
        } else {
          v += res[(size_t)row * 1024 + col];
          outf[(size_t)row * 1024 + col] = v;
        }
      }
    }
  }
}

// ---------------------------------------------------------------------------
// MFMA flash attention (unchanged from round 10).
// ---------------------------------------------------------------------------
__global__ __launch_bounds__(256) void attn_kernel(
    const _Float16* __restrict__ q, const _Float16* __restrict__ k,
    const _Float16* __restrict__ vt, _Float16* __restrict__ ctx) {
  __shared__ __align__(16) _Float16 Ks[2][64 * 64];
  __shared__ __align__(16) _Float16 Vs[2][64 * 64];
  __shared__ __align__(16) _Float16 Ps[64 * 72];
  __shared__ float Lpart[4][64];
  const int tid = threadIdx.x;
  const int w = tid >> 6, lane = tid & 63;
  const int l15 = lane & 15, q8 = lane >> 4;
  const int bh = blockIdx.y;
  const int pr = blockIdx.x;
  const size_t base = (size_t)bh * SEQT * HDIM;

  const _Float16* gk0[2]; const _Float16* gv0[2]; int ldsc[2];
#pragma unroll
  for (int i = 0; i < 2; ++i) {
    int c = i * 256 + w * 64 + lane;
    int r = c >> 3, gc = ((c & 7) ^ (r & 7)) * 8;
    gk0[i] = k + base + (size_t)r * HDIM + gc;
    gv0[i] = vt + base + (size_t)r * SEQT + gc;
    ldsc[i] = c * 8;
  }
  auto stage = [&](int kt, int buf) {
#pragma unroll
    for (int i = 0; i < 2; ++i) {
      llds16(gk0[i] + (size_t)kt * (64 * HDIM), &Ks[buf][ldsc[i]]);
      llds16(gv0[i] + kt * 64, &Vs[buf][ldsc[i]]);
    }
  };

  const int rswA = (l15 & 7);
  const int cs0 = (q8 ^ rswA) * 8;
  const int cs1 = ((4 + q8) ^ rswA) * 8;

  int s = 0;
  stage(0, 0);
  __syncthreads();
  for (int ph = 0; ph < 2; ++ph) {
    const int qtile = ph ? 31 - pr : pr;
    const int ntile = qtile + 1;
    half8 bq[4][2];
#pragma unroll
    for (int nt = 0; nt < 4; ++nt) {
      const half8* qp = (const half8*)(q + base + (size_t)(qtile * 64 + nt * 16 + l15) * HDIM);
      bq[nt][0] = qp[q8];
      bq[nt][1] = qp[4 + q8];
    }
    floatx4 acc[4];
#pragma unroll
    for (int j = 0; j < 4; ++j) acc[j] = (floatx4){0.f, 0.f, 0.f, 0.f};
    float lsum[4] = {0.f, 0.f, 0.f, 0.f};

    for (int jt = 0; jt < ntile; ++jt, ++s) {
      const int buf = s & 1;
      if (s + 1 < 33) {
        int sn = s + 1;
        int nkt = (sn <= pr) ? sn : sn - (pr + 1);
        stage(nkt, buf ^ 1);
      }
      half8 ak0 = *(const half8*)&Ks[buf][(w * 16 + l15) * 64 + cs0];
      half8 ak1 = *(const half8*)&Ks[buf][(w * 16 + l15) * 64 + cs1];
      floatx4 sv[4];
#pragma unroll
      for (int nt = 0; nt < 4; ++nt) {
        sv[nt] = __builtin_amdgcn_mfma_f32_16x16x32_f16(ak0, bq[nt][0],
                                                        (floatx4){0.f, 0.f, 0.f, 0.f}, 0, 0, 0);
        sv[nt] = __builtin_amdgcn_mfma_f32_16x16x32_f16(ak1, bq[nt][1], sv[nt], 0, 0, 0);
      }
      const bool diag = (jt == ntile - 1);
#pragma unroll
      for (int nt = 0; nt < 4; ++nt) {
        half4v phv;
#pragma unroll
        for (int r = 0; r < 4; ++r) {
          float p = __expf(sv[nt][r] * 0.125f);
          if (diag) {
            p = (w * 16 + q8 * 4 + r <= nt * 16 + l15) ? p : 0.f;
          }
          lsum[nt] += p;
          phv[r] = (_Float16)p;
        }
        *(half4v*)&Ps[(nt * 16 + l15) * 72 + w * 16 + q8 * 4] = phv;
      }
      asm volatile("s_waitcnt lgkmcnt(0)" ::: "memory");
      __builtin_amdgcn_s_barrier();
      asm volatile("" ::: "memory");
      half8 ap0 = *(const half8*)&Ps[(w * 16 + l15) * 72 + q8 * 8];
      half8 ap1 = *(const half8*)&Ps[(w * 16 + l15) * 72 + 32 + q8 * 8];
#pragma unroll
      for (int ntd = 0; ntd < 4; ++ntd) {
        half8 bv0 = *(const half8*)&Vs[buf][(ntd * 16 + l15) * 64 + cs0];
        half8 bv1 = *(const half8*)&Vs[buf][(ntd * 16 + l15) * 64 + cs1];
        acc[ntd] = __builtin_amdgcn_mfma_f32_16x16x32_f16(ap0, bv0, acc[ntd], 0, 0, 0);
        acc[ntd] = __builtin_amdgcn_mfma_f32_16x16x32_f16(ap1, bv1, acc[ntd], 0, 0, 0);
      }
      __syncthreads();
    }

#pragma unroll
    for (int nt = 0; nt < 4; ++nt) {
      lsum[nt] += __shfl_xor(lsum[nt], 16);
      lsum[nt] += __shfl_xor(lsum[nt], 32);
      if (q8 == 0) Lpart[w][nt * 16 + l15] = lsum[nt];
    }
    __syncthreads();
    const int b = bh >> 4, h = bh & 15;
#pragma unroll
    for (int r = 0; r < 4; ++r) {
      int qr = w * 16 + q8 * 4 + r;
      float inv = 1.0f / (Lpart[0][qr] + Lpart[1][qr] + Lpart[2][qr] + Lpart[3][qr]);
      int tg = qtile * 64 + qr;
      _Float16* op = ctx + ((size_t)(b * SEQT + tg)) * DMODEL + h * HDIM;
#pragma unroll
      for (int ntd = 0; ntd < 4; ++ntd)
        op[ntd * 16 + l15] = (_Float16)(acc[ntd][r] * inv);
    }
  }
}

// ---------------------------------------------------------------------------
// Host launch. Workspace layout (88 MB, aliased over the timeline):
//  [0,24M)   wt      : transposed f16 weights (W1^T @ byte 8M is dead after
//                      the W1 GEMM -> reused as W2 split-K partial p1)
//  [24,32M)  h16     : LN1 out -> ctx16 after QKV; dead after Wo -> p2
//  [32,56M)  q,k,vt  : f16 -> [32,48M) x1 (fp32), [48,56M) h2 (f16; dead
//                      after W1 GEMM -> p3)
//  [56,88M)  mid16   : f16 [4096,4096]
// All partial regions are rewritten by earlier kernels on the next graph
// replay (wtrans/ln1/ln2), so within-iteration reuse is safe.
// ---------------------------------------------------------------------------
extern "C" void kernel_launch(void* const* d_in, const int* in_sizes, int n_in,
                              void* d_out, int out_size, void* d_ws, size_t ws_size,
                              hipStream_t stream) {
  (void)in_sizes; (void)n_in; (void)out_size; (void)ws_size;
  const float* x    = (const float*)d_in[0];
  const float* ln1g = (const float*)d_in[1];
  const float* ln1b = (const float*)d_in[2];
  const float* Wq   = (const float*)d_in[3];
  const float* bq   = (const float*)d_in[4];
  const float* Wk   = (const float*)d_in[5];
  const float* bk   = (const float*)d_in[6];
  const float* Wv   = (const float*)d_in[7];
  const float* bv   = (const float*)d_in[8];
  const float* Wo   = (const float*)d_in[9];
  const float* bo   = (const float*)d_in[10];
  const float* ln2g = (const float*)d_in[11];
  const float* ln2b = (const float*)d_in[12];
  const float* W1   = (const float*)d_in[13];
  const float* b1   = (const float*)d_in[14];
  const float* W2   = (const float*)d_in[15];
  const float* b2   = (const float*)d_in[16];
  float* out = (float*)d_out;

  char* ws = (char*)d_ws;
  _Float16* wt    = (_Float16*)(ws);
  _Float16* h16   = (_Float16*)(ws + ((size_t)24 << 20));
  _Float16* qkv   = (_Float16*)(ws + ((size_t)32 << 20));
  _Float16* ctx16 = (_Float16*)(ws + ((size_t)24 << 20));  // reuse h16
  float*    x1    = (float*)   (ws + ((size_t)32 << 20));  // reuse q,k
  _Float16* h2    = (_Float16*)(ws + ((size_t)48 << 20));  // reuse vt
  _Float16* mid   = (_Float16*)(ws + ((size_t)56 << 20));
  _Float16* part1 = (_Float16*)(ws + ((size_t)8 << 20));   // dead W1^T region
  _Float16* part2 = (_Float16*)(ws + ((size_t)24 << 20));  // dead h16/ctx16
  _Float16* part3 = (_Float16*)(ws + ((size_t)48 << 20));  // dead h2

  const size_t QKV1 = (size_t)NTOK * DMODEL;  // 4M elements per matrix

  wtrans_kernel<<<12288, 256, 0, stream>>>(Wq, Wk, Wv, Wo, W1, W2, wt);
  ln_kernel<<<NTOK, 256, 0, stream>>>(x, ln1g, ln1b, h16);
  gemm_kernel<0><<<dim3(32, 24), 256, 0, stream>>>(
      h16, wt, 1024, bq, bk, bv, nullptr, nullptr, qkv);
  attn_kernel<<<dim3(16, 32), 256, 0, stream>>>(
      qkv, qkv + QKV1, qkv + 2 * QKV1, ctx16);
  gemm_kernel<1><<<dim3(32, 16), 256, 0, stream>>>(
      ctx16, wt + (size_t)3 * 1024 * 1024, 1024, bo, nullptr, nullptr, x, x1, nullptr);
  ln_kernel<<<NTOK, 256, 0, stream>>>(x1, ln2g, ln2b, h2);
  // W1: 256^2 8-phase, grid 16x16 = 256 blocks = 1/CU
  gemm256_kernel<0><<<dim3(16, 16), 512, 0, stream>>>(
      h2, wt + (size_t)4 * 1024 * 1024, 1024, b1, nullptr, nullptr, mid,
      nullptr, nullptr, nullptr);
  // W2: 256^2 8-phase split-K=4, grid 16x4x4 = 256 blocks = 1/CU
  gemm256_kernel<1><<<dim3(16, 4, 4), 512, 0, stream>>>(
      mid, wt + (size_t)8 * 1024 * 1024, 4096, b2, x1, out, nullptr,
      part1, part2, part3);
  redux_kernel<<<4096, 256, 0, stream>>>(out, part1, part2, part3);
}

// Round 7
// 353.254 us; speedup vs baseline: 1.0590x; 1.0590x over previous
//
#include <hip/hip_runtime.h>
#include <math.h>

// ---------------------------------------------------------------------------
// TransformerBlock: B=2, T=2048, D=1024, H=16, HD=64, pre-LN, causal attn, GELU
// Round 12 (base = r9 GEMM loops + r10 attn = best-of, ~354us):
//  1. Wo/W2 -> gemmw_kernel: BK=64 (nk halved -> half the barrier/drain
//     overhead), same dbuf+single-__syncthreads structure, 8-chunk XOR swizzle
//     (slot = c ^ (row&7), pre-swizzled global source, linear LDS dest).
//  2. prep_kernel: fused LN1 + weight-transpose. wtrans rewritten on 64x64
//     tiles with half8 (16B/lane) coalesced writes (old: 2B/lane).
//  3. QKV epilogue: V-transposed stores packed as half4 (rows r=0..3 are
//     contiguous tt in [B,H,HD,T]).
// Attention = r10 (barrier-A lgkmcnt-only). QKV/W1 GEMM loops = r9 verbatim.
// ---------------------------------------------------------------------------

typedef _Float16 half8 __attribute__((ext_vector_type(8)));
typedef _Float16 half4v __attribute__((ext_vector_type(4)));
typedef float floatx4 __attribute__((ext_vector_type(4)));

#define DMODEL 1024
#define SEQT   2048
#define NTOK   4096   // B*T
#define NHEAD  16
#define HDIM   64

// Async global->LDS, 16B/lane. LDS dest = wave-uniform base + lane*16 [m104].
__device__ __forceinline__ void llds16(const _Float16* g, _Float16* l) {
  __builtin_amdgcn_global_load_lds(
      (const __attribute__((address_space(1))) void*)g,
      (__attribute__((address_space(3))) void*)l, 16, 0, 0);
}

// ---------------------------------------------------------------------------
// prep_kernel: blocks [0,4096) = LayerNorm1 rows; blocks [4096,7168) =
// weight convert+transpose on 64x64 tiles with vectorized f16 writes.
// wt layout (elements): Wq^T @0, Wk^T @1M, Wv^T @2M, Wo^T @3M,
//                       W1^T @4M (4096x1024), W2^T @8M (1024x4096).
// ---------------------------------------------------------------------------
__global__ __launch_bounds__(256) void prep_kernel(
    const float* __restrict__ x, const float* __restrict__ g,
    const float* __restrict__ b, _Float16* __restrict__ h16out,
    const float* __restrict__ Wq, const float* __restrict__ Wk,
    const float* __restrict__ Wv, const float* __restrict__ Wo,
    const float* __restrict__ W1, const float* __restrict__ W2,
    _Float16* __restrict__ wt_base) {
  const int t256 = threadIdx.x;
  if (blockIdx.x < 4096) {
    // ---- LayerNorm (row = blockIdx.x) ----
    int row = blockIdx.x;
    const float4 xv = ((const float4*)(x + (size_t)row * DMODEL))[t256];
    float s = xv.x + xv.y + xv.z + xv.w;
    float s2 = xv.x * xv.x + xv.y * xv.y + xv.z * xv.z + xv.w * xv.w;
#pragma unroll
    for (int off = 32; off; off >>= 1) {
      s += __shfl_down(s, off);
      s2 += __shfl_down(s2, off);
    }
    __shared__ float red[8];
    int wid = t256 >> 6;
    if ((t256 & 63) == 0) { red[wid] = s; red[wid + 4] = s2; }
    __syncthreads();
    s = red[0] + red[1] + red[2] + red[3];
    s2 = red[4] + red[5] + red[6] + red[7];
    float mu = s * (1.0f / DMODEL);
    float var = s2 * (1.0f / DMODEL) - mu * mu;
    float rstd = rsqrtf(var + 1e-5f);
    const float4 gv = ((const float4*)g)[t256];
    const float4 bv = ((const float4*)b)[t256];
    half4v o;
    o[0] = (_Float16)((xv.x - mu) * rstd * gv.x + bv.x);
    o[1] = (_Float16)((xv.y - mu) * rstd * gv.y + bv.y);
    o[2] = (_Float16)((xv.z - mu) * rstd * gv.z + bv.z);
    o[3] = (_Float16)((xv.w - mu) * rstd * gv.w + bv.w);
    *(half4v*)(h16out + (size_t)row * DMODEL + t256 * 4) = o;
    return;
  }
  // ---- weight transpose, 64x64 fp32 tile -> f16 [N][K] ----
  __shared__ float lb[64][65];
  int id = blockIdx.x - 4096;
  const float* src; _Float16* dst; int K, N, t;
  if (id < 1024) {
    int s = id >> 8;
    src = (s == 0) ? Wq : (s == 1) ? Wk : (s == 2) ? Wv : Wo;
    dst = wt_base + (size_t)s * (1024 * 1024);
    K = 1024; N = 1024; t = id & 255;
  } else if (id < 2048) {
    src = W1; dst = wt_base + (size_t)4 * 1024 * 1024; K = 1024; N = 4096; t = id - 1024;
  } else {
    src = W2; dst = wt_base + (size_t)8 * 1024 * 1024; K = 4096; N = 1024; t = id - 2048;
  }
  int tilesN = N >> 6;
  int tk = t / tilesN, tn = t % tilesN;
#pragma unroll
  for (int i = 0; i < 4; ++i) {
    int row = i * 16 + (t256 >> 4);
    int c4 = (t256 & 15) * 4;
    float4 v = *(const float4*)&src[(size_t)(tk * 64 + row) * N + tn * 64 + c4];
    lb[row][c4] = v.x; lb[row][c4 + 1] = v.y;
    lb[row][c4 + 2] = v.z; lb[row][c4 + 3] = v.w;
  }
  __syncthreads();
  {
    int r = t256 >> 2, cb = t256 & 3;
    half8 h0, h1;
#pragma unroll
    for (int kk = 0; kk < 8; ++kk) h0[kk] = (_Float16)lb[cb * 16 + kk][r];
#pragma unroll
    for (int kk = 0; kk < 8; ++kk) h1[kk] = (_Float16)lb[cb * 16 + 8 + kk][r];
    _Float16* dp = dst + (size_t)(tn * 64 + r) * K + tk * 64 + cb * 16;
    *(half8*)dp = h0;
    *(half8*)(dp + 8) = h1;
  }
}

// ---------------------------------------------------------------------------
// LayerNorm (standalone, for LN2): fp32 in -> f16 out. One row per block.
// ---------------------------------------------------------------------------
__global__ __launch_bounds__(256) void ln_kernel(
    const float* __restrict__ x, const float* __restrict__ g,
    const float* __restrict__ b, _Float16* __restrict__ out) {
  int row = blockIdx.x;
  int t = threadIdx.x;
  const float4 xv = ((const float4*)(x + (size_t)row * DMODEL))[t];
  float s = xv.x + xv.y + xv.z + xv.w;
  float s2 = xv.x * xv.x + xv.y * xv.y + xv.z * xv.z + xv.w * xv.w;
#pragma unroll
  for (int off = 32; off; off >>= 1) {
    s += __shfl_down(s, off);
    s2 += __shfl_down(s2, off);
  }
  __shared__ float red[8];
  int wid = t >> 6;
  if ((t & 63) == 0) { red[wid] = s; red[wid + 4] = s2; }
  __syncthreads();
  s = red[0] + red[1] + red[2] + red[3];
  s2 = red[4] + red[5] + red[6] + red[7];
  float mu = s * (1.0f / DMODEL);
  float var = s2 * (1.0f / DMODEL) - mu * mu;
  float rstd = rsqrtf(var + 1e-5f);
  const float4 gv = ((const float4*)g)[t];
  const float4 bv = ((const float4*)b)[t];
  half4v o;
  o[0] = (_Float16)((xv.x - mu) * rstd * gv.x + bv.x);
  o[1] = (_Float16)((xv.y - mu) * rstd * gv.y + bv.y);
  o[2] = (_Float16)((xv.z - mu) * rstd * gv.z + bv.z);
  o[3] = (_Float16)((xv.w - mu) * rstd * gv.w + bv.w);
  *(half4v*)(out + (size_t)row * DMODEL + t * 4) = o;
}

// ---------------------------------------------------------------------------
// f16 MFMA GEMM (QKV + W1): tiles 128x128, K-tile 32, dbuf + __syncthreads
// (r9 proven loop). LDS XOR swizzle: chunk c of row r at slot c ^ ((r>>1)&3);
// staging pre-swizzles the GLOBAL source chunk (LDS dest linear per m104);
// fragment reads apply the same XOR. Conflict-free (measured 6.29M -> 0).
// MODE 0: QKV fused; q,k scatter [B,H,T,HD]; v scatters TRANSPOSED [B,H,HD,T]
//         (v stores packed as half4: rows r=0..3 are contiguous tt).
// MODE 2: bias + fast GELU; f16 output, row stride 4096.
// ---------------------------------------------------------------------------
template <int MODE>
__global__ __launch_bounds__(256) void gemm_kernel(
    const _Float16* __restrict__ A, const _Float16* __restrict__ Bt0, int K,
    const float* __restrict__ bias0, const float* __restrict__ bias1,
    const float* __restrict__ bias2,
    _Float16* __restrict__ outh) {
  __shared__ __align__(16) _Float16 As[2][128 * 32];
  __shared__ __align__(16) _Float16 Bs[2][128 * 32];
  const int tid = threadIdx.x;
  const int m0 = blockIdx.x * 128;
  const _Float16* Bt;
  const float* bias;
  _Float16* outh_sel = outh;
  int n0, sel = 0;
  if (MODE == 0) {
    sel = blockIdx.y >> 3;
    n0 = (blockIdx.y & 7) * 128;
    Bt = Bt0 + (size_t)sel * (1024 * 1024);
    bias = (sel == 0) ? bias0 : (sel == 1) ? bias1 : bias2;
    outh_sel = outh + (size_t)sel * ((size_t)NTOK * DMODEL);
  } else {
    n0 = blockIdx.y * 128;
    Bt = Bt0;
    bias = bias0;
  }
  const int w = tid >> 6, lane = tid & 63;
  const int l15 = lane & 15, q8 = lane >> 4;
  const int wrow = (w >> 1) * 64;
  const int wcol = (w & 1) * 64;
  const int csw = (q8 ^ ((l15 >> 1) & 3)) * 8;

  const _Float16* gA[2]; int ldsA[2];
  const _Float16* gB[2]; int ldsB[2];
#pragma unroll
  for (int i = 0; i < 2; ++i) {
    int c0 = i * 256 + w * 64;
    int idx = c0 + lane;
    int m = idx >> 2;
    int kq = ((idx & 3) ^ ((m >> 1) & 3)) * 8;
    gA[i] = A + (size_t)(m0 + m) * K + kq;
    ldsA[i] = c0 * 8;
    gB[i] = Bt + (size_t)(n0 + m) * K + kq;
    ldsB[i] = c0 * 8;
  }

  auto stage = [&](int buf) {
#pragma unroll
    for (int i = 0; i < 2; ++i) {
      llds16(gA[i], &As[buf][ldsA[i] + lane * 8]);
      gA[i] += 32;
    }
#pragma unroll
    for (int i = 0; i < 2; ++i) {
      llds16(gB[i], &Bs[buf][ldsB[i] + lane * 8]);
      gB[i] += 32;
    }
  };

  floatx4 acc[4][4];
#pragma unroll
  for (int i = 0; i < 4; ++i)
#pragma unroll
    for (int j = 0; j < 4; ++j) acc[i][j] = (floatx4){0.f, 0.f, 0.f, 0.f};

  const int nk = K >> 5;
  stage(0);
  __syncthreads();
  for (int t = 0; t < nk; ++t) {
    const int buf = t & 1;
    if (t + 1 < nk) stage(buf ^ 1);
    half8 af[4], bf[4];
#pragma unroll
    for (int i = 0; i < 4; ++i)
      af[i] = *(const half8*)&As[buf][(wrow + i * 16 + l15) * 32 + csw];
#pragma unroll
    for (int j = 0; j < 4; ++j)
      bf[j] = *(const half8*)&Bs[buf][(wcol + j * 16 + l15) * 32 + csw];
#pragma unroll
    for (int i = 0; i < 4; ++i)
#pragma unroll
      for (int j = 0; j < 4; ++j)
        acc[i][j] = __builtin_amdgcn_mfma_f32_16x16x32_f16(af[i], bf[j], acc[i][j], 0, 0, 0);
    __syncthreads();
  }

  // Epilogue. C/D layout: col = lane&15, row = (lane>>4)*4 + reg   [m89/m91]
#pragma unroll
  for (int i = 0; i < 4; ++i) {
    int rowb = m0 + wrow + i * 16 + q8 * 4;
#pragma unroll
    for (int j = 0; j < 4; ++j) {
      int col = n0 + wcol + j * 16 + l15;
      float bval = bias[col];
      if (MODE == 0 && sel == 2) {
        // V transposed [B,H,HD,T]: rows r=0..3 -> tt0..tt0+3 contiguous
        int bb = rowb >> 11, tt0 = rowb & 2047;
        int hh = col >> 6, hd = col & 63;
        half4v hv;
#pragma unroll
        for (int r = 0; r < 4; ++r) hv[r] = (_Float16)(acc[i][j][r] + bval);
        *(half4v*)&outh_sel[((size_t)(bb * NHEAD + hh) * HDIM + hd) * SEQT + tt0] = hv;
      } else {
#pragma unroll
        for (int r = 0; r < 4; ++r) {
          int row = rowb + r;
          float v = acc[i][j][r] + bval;
          if (MODE == 0) {
            int bb = row >> 11, tt = row & 2047;
            int hh = col >> 6, hd = col & 63;
            outh_sel[((size_t)(bb * NHEAD + hh) * SEQT + tt) * HDIM + hd] = (_Float16)v;
          } else {
            // fast GELU: v*sigmoid(1.5957691(v + 0.044715 v^3)); |err| < 0.003
            float z = 1.5957691216f * v * (1.0f + 0.044715f * v * v);
            float gl = v / (1.0f + __expf(-z));
            outh[(size_t)row * 4096 + col] = (_Float16)gl;
          }
        }
      }
    }
  }
}

// ---------------------------------------------------------------------------
// gemmw_kernel (Wo + W2): C[4096,N] = A @ Bt^T, 128x64 tile, BK=64.
// Same dbuf + single-__syncthreads structure as r9 (proven), but half the
// K-steps -> half the per-step barrier/drain overhead.
// Swizzle: row = 64 f16 = 8 chunks of 16B; LDS slot s of row r holds global
// chunk s ^ (r&7) (pre-swizzled source, linear LDS dest per m104). Fragment
// read of global chunk G=(kh*4+q8) of row r uses slot G ^ (r&7). Bank math:
// 16 lanes -> 8 slots x 2 lanes = 2-way (free, m136).
// Epilogue: bias + residual(fp32), fp32 out row stride 1024.
// ---------------------------------------------------------------------------
__global__ __launch_bounds__(256) void gemmw_kernel(
    const _Float16* __restrict__ A, const _Float16* __restrict__ Bt, int K,
    const float* __restrict__ bias, const float* __restrict__ res,
    float* __restrict__ outf) {
  __shared__ __align__(16) _Float16 As[2][128 * 64];
  __shared__ __align__(16) _Float16 Bs[2][64 * 64];
  const int tid = threadIdx.x;
  const int m0 = blockIdx.x * 128;
  const int n0 = blockIdx.y * 64;
  const int w = tid >> 6, lane = tid & 63;
  const int l15 = lane & 15, q8 = lane >> 4;
  const int wrow = w * 32;

  const _Float16* gA[4]; int la[4];
  const _Float16* gB[2]; int lb2[2];
#pragma unroll
  for (int i = 0; i < 4; ++i) {
    int c = i * 256 + tid;
    int r = c >> 3, gc = ((c & 7) ^ (r & 7)) * 8;
    gA[i] = A + (size_t)(m0 + r) * K + gc;
    la[i] = c * 8;
  }
#pragma unroll
  for (int i = 0; i < 2; ++i) {
    int c = i * 256 + tid;
    int r = c >> 3, gc = ((c & 7) ^ (r & 7)) * 8;
    gB[i] = Bt + (size_t)(n0 + r) * K + gc;
    lb2[i] = c * 8;
  }
  auto stage = [&](int buf) {
#pragma unroll
    for (int i = 0; i < 4; ++i) {
      llds16(gA[i], &As[buf][la[i]]);
      gA[i] += 64;
    }
#pragma unroll
    for (int i = 0; i < 2; ++i) {
      llds16(gB[i], &Bs[buf][lb2[i]]);
      gB[i] += 64;
    }
  };

  floatx4 acc[2][4];
#pragma unroll
  for (int i = 0; i < 2; ++i)
#pragma unroll
    for (int j = 0; j < 4; ++j) acc[i][j] = (floatx4){0.f, 0.f, 0.f, 0.f};

  const int nk = K >> 6;
  stage(0);
  __syncthreads();
  for (int t = 0; t < nk; ++t) {
    const int buf = t & 1;
    if (t + 1 < nk) stage(buf ^ 1);  // async, in flight during compute
    half8 af[2][2], bf[4][2];
#pragma unroll
    for (int i = 0; i < 2; ++i) {
      int rA = wrow + i * 16 + l15;
#pragma unroll
      for (int kh = 0; kh < 2; ++kh) {
        int sl = ((kh * 4 + q8) ^ (rA & 7)) * 8;
        af[i][kh] = *(const half8*)&As[buf][rA * 64 + sl];
      }
    }
#pragma unroll
    for (int j = 0; j < 4; ++j) {
      int rB = j * 16 + l15;
#pragma unroll
      for (int kh = 0; kh < 2; ++kh) {
        int sl = ((kh * 4 + q8) ^ (rB & 7)) * 8;
        bf[j][kh] = *(const half8*)&Bs[buf][rB * 64 + sl];
      }
    }
#pragma unroll
    for (int i = 0; i < 2; ++i)
#pragma unroll
      for (int j = 0; j < 4; ++j) {
        acc[i][j] = __builtin_amdgcn_mfma_f32_16x16x32_f16(af[i][0], bf[j][0], acc[i][j], 0, 0, 0);
        acc[i][j] = __builtin_amdgcn_mfma_f32_16x16x32_f16(af[i][1], bf[j][1], acc[i][j], 0, 0, 0);
      }
    __syncthreads();
  }

  // Epilogue: bias + residual, fp32 out.
#pragma unroll
  for (int i = 0; i < 2; ++i) {
    int rowb = m0 + wrow + i * 16 + q8 * 4;
#pragma unroll
    for (int j = 0; j < 4; ++j) {
      int col = n0 + j * 16 + l15;
      float bval = bias[col];
#pragma unroll
      for (int r = 0; r < 4; ++r) {
        int row = rowb + r;
        float v = acc[i][j][r] + bval + res[(size_t)row * 1024 + col];
        outf[(size_t)row * 1024 + col] = v;
      }
    }
  }
}

// ---------------------------------------------------------------------------
// MFMA flash attention (r10 version: barrier-A is lgkmcnt(0)+s_barrier only).
// ---------------------------------------------------------------------------
__global__ __launch_bounds__(256) void attn_kernel(
    const _Float16* __restrict__ q, const _Float16* __restrict__ k,
    const _Float16* __restrict__ vt, _Float16* __restrict__ ctx) {
  __shared__ __align__(16) _Float16 Ks[2][64 * 64];
  __shared__ __align__(16) _Float16 Vs[2][64 * 64];
  __shared__ __align__(16) _Float16 Ps[64 * 72];
  __shared__ float Lpart[4][64];
  const int tid = threadIdx.x;
  const int w = tid >> 6, lane = tid & 63;
  const int l15 = lane & 15, q8 = lane >> 4;
  const int bh = blockIdx.y;
  const int pr = blockIdx.x;
  const size_t base = (size_t)bh * SEQT * HDIM;

  const _Float16* gk0[2]; const _Float16* gv0[2]; int ldsc[2];
#pragma unroll
  for (int i = 0; i < 2; ++i) {
    int c = i * 256 + w * 64 + lane;
    int r = c >> 3, gc = ((c & 7) ^ (r & 7)) * 8;
    gk0[i] = k + base + (size_t)r * HDIM + gc;
    gv0[i] = vt + base + (size_t)r * SEQT + gc;
    ldsc[i] = c * 8;
  }
  auto stage = [&](int kt, int buf) {
#pragma unroll
    for (int i = 0; i < 2; ++i) {
      llds16(gk0[i] + (size_t)kt * (64 * HDIM), &Ks[buf][ldsc[i]]);
      llds16(gv0[i] + kt * 64, &Vs[buf][ldsc[i]]);
    }
  };

  const int rswA = (l15 & 7);
  const int cs0 = (q8 ^ rswA) * 8;
  const int cs1 = ((4 + q8) ^ rswA) * 8;

  int s = 0;
  stage(0, 0);
  __syncthreads();
  for (int ph = 0; ph < 2; ++ph) {
    const int qtile = ph ? 31 - pr : pr;
    const int ntile = qtile + 1;
    half8 bq[4][2];
#pragma unroll
    for (int nt = 0; nt < 4; ++nt) {
      const half8* qp = (const half8*)(q + base + (size_t)(qtile * 64 + nt * 16 + l15) * HDIM);
      bq[nt][0] = qp[q8];
      bq[nt][1] = qp[4 + q8];
    }
    floatx4 acc[4];
#pragma unroll
    for (int j = 0; j < 4; ++j) acc[j] = (floatx4){0.f, 0.f, 0.f, 0.f};
    float lsum[4] = {0.f, 0.f, 0.f, 0.f};

    for (int jt = 0; jt < ntile; ++jt, ++s) {
      const int buf = s & 1;
      if (s + 1 < 33) {
        int sn = s + 1;
        int nkt = (sn <= pr) ? sn : sn - (pr + 1);
        stage(nkt, buf ^ 1);  // async, in flight during S^T AND PV
      }
      half8 ak0 = *(const half8*)&Ks[buf][(w * 16 + l15) * 64 + cs0];
      half8 ak1 = *(const half8*)&Ks[buf][(w * 16 + l15) * 64 + cs1];
      floatx4 sv[4];
#pragma unroll
      for (int nt = 0; nt < 4; ++nt) {
        sv[nt] = __builtin_amdgcn_mfma_f32_16x16x32_f16(ak0, bq[nt][0],
                                                        (floatx4){0.f, 0.f, 0.f, 0.f}, 0, 0, 0);
        sv[nt] = __builtin_amdgcn_mfma_f32_16x16x32_f16(ak1, bq[nt][1], sv[nt], 0, 0, 0);
      }
      const bool diag = (jt == ntile - 1);
#pragma unroll
      for (int nt = 0; nt < 4; ++nt) {
        half4v phv;
#pragma unroll
        for (int r = 0; r < 4; ++r) {
          float p = __expf(sv[nt][r] * 0.125f);
          if (diag) {
            p = (w * 16 + q8 * 4 + r <= nt * 16 + l15) ? p : 0.f;
          }
          lsum[nt] += p;
          phv[r] = (_Float16)p;
        }
        *(half4v*)&Ps[(nt * 16 + l15) * 72 + w * 16 + q8 * 4] = phv;
      }
      // barrier A: P visible (LDS only); K/V prefetch vmem stays in flight
      asm volatile("s_waitcnt lgkmcnt(0)" ::: "memory");
      __builtin_amdgcn_s_barrier();
      asm volatile("" ::: "memory");
      half8 ap0 = *(const half8*)&Ps[(w * 16 + l15) * 72 + q8 * 8];
      half8 ap1 = *(const half8*)&Ps[(w * 16 + l15) * 72 + 32 + q8 * 8];
#pragma unroll
      for (int ntd = 0; ntd < 4; ++ntd) {
        half8 bv0 = *(const half8*)&Vs[buf][(ntd * 16 + l15) * 64 + cs0];
        half8 bv1 = *(const half8*)&Vs[buf][(ntd * 16 + l15) * 64 + cs1];
        acc[ntd] = __builtin_amdgcn_mfma_f32_16x16x32_f16(ap0, bv0, acc[ntd], 0, 0, 0);
        acc[ntd] = __builtin_amdgcn_mfma_f32_16x16x32_f16(ap1, bv1, acc[ntd], 0, 0, 0);
      }
      __syncthreads();  // barrier B: readers done; prefetch drained
    }

#pragma unroll
    for (int nt = 0; nt < 4; ++nt) {
      lsum[nt] += __shfl_xor(lsum[nt], 16);
      lsum[nt] += __shfl_xor(lsum[nt], 32);
      if (q8 == 0) Lpart[w][nt * 16 + l15] = lsum[nt];
    }
    __syncthreads();
    const int b = bh >> 4, h = bh & 15;
#pragma unroll
    for (int r = 0; r < 4; ++r) {
      int qr = w * 16 + q8 * 4 + r;
      float inv = 1.0f / (Lpart[0][qr] + Lpart[1][qr] + Lpart[2][qr] + Lpart[3][qr]);
      int tg = qtile * 64 + qr;
      _Float16* op = ctx + ((size_t)(b * SEQT + tg)) * DMODEL + h * HDIM;
#pragma unroll
      for (int ntd = 0; ntd < 4; ++ntd)
        op[ntd * 16 + l15] = (_Float16)(acc[ntd][r] * inv);
    }
  }
}

// ---------------------------------------------------------------------------
// Host launch. Workspace layout (88 MB, aliased over the timeline):
//  [0,24M)   wt      : transposed f16 weights (persistent)
//  [24,32M)  h16     : LN1 out -> reused as ctx16 after QKV GEMM reads it
//  [32,56M)  q,k,vt  : f16; q,k [B,H,T,HD], v transposed [B,H,HD,T]
//                      -> [32,48M) reused as x1 (fp32), [48,56M) as h2 (f16)
//  [56,88M)  mid16   : f16 [4096,4096]
// ---------------------------------------------------------------------------
extern "C" void kernel_launch(void* const* d_in, const int* in_sizes, int n_in,
                              void* d_out, int out_size, void* d_ws, size_t ws_size,
                              hipStream_t stream) {
  (void)in_sizes; (void)n_in; (void)out_size; (void)ws_size;
  const float* x    = (const float*)d_in[0];
  const float* ln1g = (const float*)d_in[1];
  const float* ln1b = (const float*)d_in[2];
  const float* Wq   = (const float*)d_in[3];
  const float* bq   = (const float*)d_in[4];
  const float* Wk   = (const float*)d_in[5];
  const float* bk   = (const float*)d_in[6];
  const float* Wv   = (const float*)d_in[7];
  const float* bv   = (const float*)d_in[8];
  const float* Wo   = (const float*)d_in[9];
  const float* bo   = (const float*)d_in[10];
  const float* ln2g = (const float*)d_in[11];
  const float* ln2b = (const float*)d_in[12];
  const float* W1   = (const float*)d_in[13];
  const float* b1   = (const float*)d_in[14];
  const float* W2   = (const float*)d_in[15];
  const float* b2   = (const float*)d_in[16];
  float* out = (float*)d_out;

  char* ws = (char*)d_ws;
  _Float16* wt    = (_Float16*)(ws);
  _Float16* h16   = (_Float16*)(ws + ((size_t)24 << 20));
  _Float16* qkv   = (_Float16*)(ws + ((size_t)32 << 20));
  _Float16* ctx16 = (_Float16*)(ws + ((size_t)24 << 20));  // reuse h16
  float*    x1    = (float*)   (ws + ((size_t)32 << 20));  // reuse q,k
  _Float16* h2    = (_Float16*)(ws + ((size_t)48 << 20));  // reuse vt
  _Float16* mid   = (_Float16*)(ws + ((size_t)56 << 20));

  const size_t QKV1 = (size_t)NTOK * DMODEL;  // 4M elements per matrix

  prep_kernel<<<7168, 256, 0, stream>>>(x, ln1g, ln1b, h16,
                                        Wq, Wk, Wv, Wo, W1, W2, wt);
  gemm_kernel<0><<<dim3(32, 24), 256, 0, stream>>>(
      h16, wt, 1024, bq, bk, bv, qkv);
  attn_kernel<<<dim3(16, 32), 256, 0, stream>>>(
      qkv, qkv + QKV1, qkv + 2 * QKV1, ctx16);
  gemmw_kernel<<<dim3(32, 16), 256, 0, stream>>>(
      ctx16, wt + (size_t)3 * 1024 * 1024, 1024, bo, x, x1);
  ln_kernel<<<NTOK, 256, 0, stream>>>(x1, ln2g, ln2b, h2);
  gemm_kernel<2><<<dim3(32, 32), 256, 0, stream>>>(
      h2, wt + (size_t)4 * 1024 * 1024, 1024, b1, nullptr, nullptr, mid);
  gemmw_kernel<<<dim3(32, 16), 256, 0, stream>>>(
      mid, wt + (size_t)8 * 1024 * 1024, 4096, b2, x1, out);
}

// Round 9
// 338.282 us; speedup vs baseline: 1.1059x; 1.0443x over previous
//
#include <hip/hip_runtime.h>
#include <math.h>

// ---------------------------------------------------------------------------
// TransformerBlock: B=2, T=2048, D=1024, H=16, HD=64, pre-LN, causal attn, GELU
// Round 14 = round 13 resubmitted verbatim (r13 bench was an infra failure:
// "MI355X container failed twice" -- no kernel signal).
// Round 13 (base = round 12, 353.3us): ALL four GEMMs unified on the gemmw
// structure (128x64 tile, BK=64, dbuf + single __syncthreads, 8-chunk XOR
// swizzle) -- the only structure with a non-negative measured delta this
// session (W2: 67.6 -> <62.6). OUTMODEs:
//   0 = bias + residual fp32 (Wo grid (32,16), W2 grid (32,16))   [r12 proven]
//   1 = bias + fast GELU f16 stride 4096 (W1, grid (32,64), 3 blk/CU)
//   2 = QKV fused: sel=y>>4, scatter q,k [B,H,T,HD] / v^T [B,H,HD,T] packed
//       (grid (32,48), 3 blk/CU)
// W1/QKV thereby go from 32 barrier steps (BK=32) to 16. Attention (r10),
// prep (r12), ln2 unchanged.
// ---------------------------------------------------------------------------

typedef _Float16 half8 __attribute__((ext_vector_type(8)));
typedef _Float16 half4v __attribute__((ext_vector_type(4)));
typedef float floatx4 __attribute__((ext_vector_type(4)));

#define DMODEL 1024
#define SEQT   2048
#define NTOK   4096   // B*T
#define NHEAD  16
#define HDIM   64

// Async global->LDS, 16B/lane. LDS dest = wave-uniform base + lane*16 [m104].
__device__ __forceinline__ void llds16(const _Float16* g, _Float16* l) {
  __builtin_amdgcn_global_load_lds(
      (const __attribute__((address_space(1))) void*)g,
      (__attribute__((address_space(3))) void*)l, 16, 0, 0);
}

// ---------------------------------------------------------------------------
// prep_kernel: blocks [0,4096) = LayerNorm1 rows; blocks [4096,7168) =
// weight convert+transpose on 64x64 tiles with vectorized f16 writes.
// wt layout (elements): Wq^T @0, Wk^T @1M, Wv^T @2M, Wo^T @3M,
//                       W1^T @4M (4096x1024), W2^T @8M (1024x4096).
// ---------------------------------------------------------------------------
__global__ __launch_bounds__(256) void prep_kernel(
    const float* __restrict__ x, const float* __restrict__ g,
    const float* __restrict__ b, _Float16* __restrict__ h16out,
    const float* __restrict__ Wq, const float* __restrict__ Wk,
    const float* __restrict__ Wv, const float* __restrict__ Wo,
    const float* __restrict__ W1, const float* __restrict__ W2,
    _Float16* __restrict__ wt_base) {
  const int t256 = threadIdx.x;
  if (blockIdx.x < 4096) {
    // ---- LayerNorm (row = blockIdx.x) ----
    int row = blockIdx.x;
    const float4 xv = ((const float4*)(x + (size_t)row * DMODEL))[t256];
    float s = xv.x + xv.y + xv.z + xv.w;
    float s2 = xv.x * xv.x + xv.y * xv.y + xv.z * xv.z + xv.w * xv.w;
#pragma unroll
    for (int off = 32; off; off >>= 1) {
      s += __shfl_down(s, off);
      s2 += __shfl_down(s2, off);
    }
    __shared__ float red[8];
    int wid = t256 >> 6;
    if ((t256 & 63) == 0) { red[wid] = s; red[wid + 4] = s2; }
    __syncthreads();
    s = red[0] + red[1] + red[2] + red[3];
    s2 = red[4] + red[5] + red[6] + red[7];
    float mu = s * (1.0f / DMODEL);
    float var = s2 * (1.0f / DMODEL) - mu * mu;
    float rstd = rsqrtf(var + 1e-5f);
    const float4 gv = ((const float4*)g)[t256];
    const float4 bv = ((const float4*)b)[t256];
    half4v o;
    o[0] = (_Float16)((xv.x - mu) * rstd * gv.x + bv.x);
    o[1] = (_Float16)((xv.y - mu) * rstd * gv.y + bv.y);
    o[2] = (_Float16)((xv.z - mu) * rstd * gv.z + bv.z);
    o[3] = (_Float16)((xv.w - mu) * rstd * gv.w + bv.w);
    *(half4v*)(h16out + (size_t)row * DMODEL + t256 * 4) = o;
    return;
  }
  // ---- weight transpose, 64x64 fp32 tile -> f16 [N][K] ----
  __shared__ float lb[64][65];
  int id = blockIdx.x - 4096;
  const float* src; _Float16* dst; int K, N, t;
  if (id < 1024) {
    int s = id >> 8;
    src = (s == 0) ? Wq : (s == 1) ? Wk : (s == 2) ? Wv : Wo;
    dst = wt_base + (size_t)s * (1024 * 1024);
    K = 1024; N = 1024; t = id & 255;
  } else if (id < 2048) {
    src = W1; dst = wt_base + (size_t)4 * 1024 * 1024; K = 1024; N = 4096; t = id - 1024;
  } else {
    src = W2; dst = wt_base + (size_t)8 * 1024 * 1024; K = 4096; N = 1024; t = id - 2048;
  }
  int tilesN = N >> 6;
  int tk = t / tilesN, tn = t % tilesN;
#pragma unroll
  for (int i = 0; i < 4; ++i) {
    int row = i * 16 + (t256 >> 4);
    int c4 = (t256 & 15) * 4;
    float4 v = *(const float4*)&src[(size_t)(tk * 64 + row) * N + tn * 64 + c4];
    lb[row][c4] = v.x; lb[row][c4 + 1] = v.y;
    lb[row][c4 + 2] = v.z; lb[row][c4 + 3] = v.w;
  }
  __syncthreads();
  {
    int r = t256 >> 2, cb = t256 & 3;
    half8 h0, h1;
#pragma unroll
    for (int kk = 0; kk < 8; ++kk) h0[kk] = (_Float16)lb[cb * 16 + kk][r];
#pragma unroll
    for (int kk = 0; kk < 8; ++kk) h1[kk] = (_Float16)lb[cb * 16 + 8 + kk][r];
    _Float16* dp = dst + (size_t)(tn * 64 + r) * K + tk * 64 + cb * 16;
    *(half8*)dp = h0;
    *(half8*)(dp + 8) = h1;
  }
}

// ---------------------------------------------------------------------------
// LayerNorm (standalone, for LN2): fp32 in -> f16 out. One row per block.
// ---------------------------------------------------------------------------
__global__ __launch_bounds__(256) void ln_kernel(
    const float* __restrict__ x, const float* __restrict__ g,
    const float* __restrict__ b, _Float16* __restrict__ out) {
  int row = blockIdx.x;
  int t = threadIdx.x;
  const float4 xv = ((const float4*)(x + (size_t)row * DMODEL))[t];
  float s = xv.x + xv.y + xv.z + xv.w;
  float s2 = xv.x * xv.x + xv.y * xv.y + xv.z * xv.z + xv.w * xv.w;
#pragma unroll
  for (int off = 32; off; off >>= 1) {
    s += __shfl_down(s, off);
    s2 += __shfl_down(s2, off);
  }
  __shared__ float red[8];
  int wid = t >> 6;
  if ((t & 63) == 0) { red[wid] = s; red[wid + 4] = s2; }
  __syncthreads();
  s = red[0] + red[1] + red[2] + red[3];
  s2 = red[4] + red[5] + red[6] + red[7];
  float mu = s * (1.0f / DMODEL);
  float var = s2 * (1.0f / DMODEL) - mu * mu;
  float rstd = rsqrtf(var + 1e-5f);
  const float4 gv = ((const float4*)g)[t];
  const float4 bv = ((const float4*)b)[t];
  half4v o;
  o[0] = (_Float16)((xv.x - mu) * rstd * gv.x + bv.x);
  o[1] = (_Float16)((xv.y - mu) * rstd * gv.y + bv.y);
  o[2] = (_Float16)((xv.z - mu) * rstd * gv.z + bv.z);
  o[3] = (_Float16)((xv.w - mu) * rstd * gv.w + bv.w);
  *(half4v*)(out + (size_t)row * DMODEL + t * 4) = o;
}

// ---------------------------------------------------------------------------
// gemmw_kernel: C[4096,N] = A @ Bt^T, 128x64 tile, BK=64, 4 waves.
// dbuf + single-__syncthreads (the r9-proven sync structure, r12-proven at
// BK=64). Swizzle: row = 64 f16 = 8 chunks of 16B; LDS slot s of row r holds
// global chunk s ^ (r&7) (pre-swizzled source, linear LDS dest per m104).
// Fragment read of global chunk G=(kh*4+q8) of row r uses slot G ^ (r&7).
// Bank math: 16 lanes -> 8 slots x 2 lanes = 2-way (free, m136).
// OUTMODE 0: bias + residual(fp32); fp32 out, row stride 1024 (Wo, W2).
// OUTMODE 1: bias + fast GELU; f16 out, row stride 4096 (W1).
// OUTMODE 2: QKV fused: sel = blockIdx.y>>4 picks {Wq,Wk,Wv}; q,k scatter
//            [B,H,T,HD]; v scatters TRANSPOSED [B,H,HD,T] with half4 pack.
// ---------------------------------------------------------------------------
template <int OUTMODE>
__global__ __launch_bounds__(256) void gemmw_kernel(
    const _Float16* __restrict__ A, const _Float16* __restrict__ Bt0, int K,
    const float* __restrict__ bias0, const float* __restrict__ bias1,
    const float* __restrict__ bias2, const float* __restrict__ res,
    float* __restrict__ outf, _Float16* __restrict__ outh) {
  __shared__ __align__(16) _Float16 As[2][128 * 64];
  __shared__ __align__(16) _Float16 Bs[2][64 * 64];
  const int tid = threadIdx.x;
  const int m0 = blockIdx.x * 128;
  const int w = tid >> 6, lane = tid & 63;
  const int l15 = lane & 15, q8 = lane >> 4;
  const int wrow = w * 32;
  const _Float16* Bt;
  const float* bias;
  _Float16* outh_sel = outh;
  int n0, sel = 0;
  if (OUTMODE == 2) {
    sel = blockIdx.y >> 4;
    n0 = (blockIdx.y & 15) * 64;
    Bt = Bt0 + (size_t)sel * (1024 * 1024);
    bias = (sel == 0) ? bias0 : (sel == 1) ? bias1 : bias2;
    outh_sel = outh + (size_t)sel * ((size_t)NTOK * DMODEL);
  } else {
    n0 = blockIdx.y * 64;
    Bt = Bt0;
    bias = bias0;
  }

  const _Float16* gA[4]; int la[4];
  const _Float16* gB[2]; int lb2[2];
#pragma unroll
  for (int i = 0; i < 4; ++i) {
    int c = i * 256 + tid;
    int r = c >> 3, gc = ((c & 7) ^ (r & 7)) * 8;
    gA[i] = A + (size_t)(m0 + r) * K + gc;
    la[i] = c * 8;
  }
#pragma unroll
  for (int i = 0; i < 2; ++i) {
    int c = i * 256 + tid;
    int r = c >> 3, gc = ((c & 7) ^ (r & 7)) * 8;
    gB[i] = Bt + (size_t)(n0 + r) * K + gc;
    lb2[i] = c * 8;
  }
  auto stage = [&](int buf) {
#pragma unroll
    for (int i = 0; i < 4; ++i) {
      llds16(gA[i], &As[buf][la[i]]);
      gA[i] += 64;
    }
#pragma unroll
    for (int i = 0; i < 2; ++i) {
      llds16(gB[i], &Bs[buf][lb2[i]]);
      gB[i] += 64;
    }
  };

  floatx4 acc[2][4];
#pragma unroll
  for (int i = 0; i < 2; ++i)
#pragma unroll
    for (int j = 0; j < 4; ++j) acc[i][j] = (floatx4){0.f, 0.f, 0.f, 0.f};

  const int nk = K >> 6;
  stage(0);
  __syncthreads();
  for (int t = 0; t < nk; ++t) {
    const int buf = t & 1;
    if (t + 1 < nk) stage(buf ^ 1);  // async, in flight during compute
    half8 af[2][2], bf[4][2];
#pragma unroll
    for (int i = 0; i < 2; ++i) {
      int rA = wrow + i * 16 + l15;
#pragma unroll
      for (int kh = 0; kh < 2; ++kh) {
        int sl = ((kh * 4 + q8) ^ (rA & 7)) * 8;
        af[i][kh] = *(const half8*)&As[buf][rA * 64 + sl];
      }
    }
#pragma unroll
    for (int j = 0; j < 4; ++j) {
      int rB = j * 16 + l15;
#pragma unroll
      for (int kh = 0; kh < 2; ++kh) {
        int sl = ((kh * 4 + q8) ^ (rB & 7)) * 8;
        bf[j][kh] = *(const half8*)&Bs[buf][rB * 64 + sl];
      }
    }
#pragma unroll
    for (int i = 0; i < 2; ++i)
#pragma unroll
      for (int j = 0; j < 4; ++j) {
        acc[i][j] = __builtin_amdgcn_mfma_f32_16x16x32_f16(af[i][0], bf[j][0], acc[i][j], 0, 0, 0);
        acc[i][j] = __builtin_amdgcn_mfma_f32_16x16x32_f16(af[i][1], bf[j][1], acc[i][j], 0, 0, 0);
      }
    __syncthreads();
  }

  // Epilogue. C/D layout: col = lane&15, row = (lane>>4)*4 + reg   [m89/m91]
#pragma unroll
  for (int i = 0; i < 2; ++i) {
    int rowb = m0 + wrow + i * 16 + q8 * 4;
#pragma unroll
    for (int j = 0; j < 4; ++j) {
      int col = n0 + j * 16 + l15;
      float bval = bias[col];
      if (OUTMODE == 2 && sel == 2) {
        // V transposed [B,H,HD,T]: rows r=0..3 -> tt0..tt0+3 contiguous
        int bb = rowb >> 11, tt0 = rowb & 2047;
        int hh = col >> 6, hd = col & 63;
        half4v hv;
#pragma unroll
        for (int r = 0; r < 4; ++r) hv[r] = (_Float16)(acc[i][j][r] + bval);
        *(half4v*)&outh_sel[((size_t)(bb * NHEAD + hh) * HDIM + hd) * SEQT + tt0] = hv;
      } else {
#pragma unroll
        for (int r = 0; r < 4; ++r) {
          int row = rowb + r;
          float v = acc[i][j][r] + bval;
          if (OUTMODE == 0) {
            v += res[(size_t)row * 1024 + col];
            outf[(size_t)row * 1024 + col] = v;
          } else if (OUTMODE == 1) {
            // fast GELU: v*sigmoid(1.5957691(v + 0.044715 v^3)); |err| < 0.003
            float z = 1.5957691216f * v * (1.0f + 0.044715f * v * v);
            float gl = v / (1.0f + __expf(-z));
            outh[(size_t)row * 4096 + col] = (_Float16)gl;
          } else {
            int bb = row >> 11, tt = row & 2047;
            int hh = col >> 6, hd = col & 63;
            outh_sel[((size_t)(bb * NHEAD + hh) * SEQT + tt) * HDIM + hd] = (_Float16)v;
          }
        }
      }
    }
  }
}

// ---------------------------------------------------------------------------
// MFMA flash attention (r10 version: barrier-A is lgkmcnt(0)+s_barrier only).
// ---------------------------------------------------------------------------
__global__ __launch_bounds__(256) void attn_kernel(
    const _Float16* __restrict__ q, const _Float16* __restrict__ k,
    const _Float16* __restrict__ vt, _Float16* __restrict__ ctx) {
  __shared__ __align__(16) _Float16 Ks[2][64 * 64];
  __shared__ __align__(16) _Float16 Vs[2][64 * 64];
  __shared__ __align__(16) _Float16 Ps[64 * 72];
  __shared__ float Lpart[4][64];
  const int tid = threadIdx.x;
  const int w = tid >> 6, lane = tid & 63;
  const int l15 = lane & 15, q8 = lane >> 4;
  const int bh = blockIdx.y;
  const int pr = blockIdx.x;
  const size_t base = (size_t)bh * SEQT * HDIM;

  const _Float16* gk0[2]; const _Float16* gv0[2]; int ldsc[2];
#pragma unroll
  for (int i = 0; i < 2; ++i) {
    int c = i * 256 + w * 64 + lane;
    int r = c >> 3, gc = ((c & 7) ^ (r & 7)) * 8;
    gk0[i] = k + base + (size_t)r * HDIM + gc;
    gv0[i] = vt + base + (size_t)r * SEQT + gc;
    ldsc[i] = c * 8;
  }
  auto stage = [&](int kt, int buf) {
#pragma unroll
    for (int i = 0; i < 2; ++i) {
      llds16(gk0[i] + (size_t)kt * (64 * HDIM), &Ks[buf][ldsc[i]]);
      llds16(gv0[i] + kt * 64, &Vs[buf][ldsc[i]]);
    }
  };

  const int rswA = (l15 & 7);
  const int cs0 = (q8 ^ rswA) * 8;
  const int cs1 = ((4 + q8) ^ rswA) * 8;

  int s = 0;
  stage(0, 0);
  __syncthreads();
  for (int ph = 0; ph < 2; ++ph) {
    const int qtile = ph ? 31 - pr : pr;
    const int ntile = qtile + 1;
    half8 bq[4][2];
#pragma unroll
    for (int nt = 0; nt < 4; ++nt) {
      const half8* qp = (const half8*)(q + base + (size_t)(qtile * 64 + nt * 16 + l15) * HDIM);
      bq[nt][0] = qp[q8];
      bq[nt][1] = qp[4 + q8];
    }
    floatx4 acc[4];
#pragma unroll
    for (int j = 0; j < 4; ++j) acc[j] = (floatx4){0.f, 0.f, 0.f, 0.f};
    float lsum[4] = {0.f, 0.f, 0.f, 0.f};

    for (int jt = 0; jt < ntile; ++jt, ++s) {
      const int buf = s & 1;
      if (s + 1 < 33) {
        int sn = s + 1;
        int nkt = (sn <= pr) ? sn : sn - (pr + 1);
        stage(nkt, buf ^ 1);  // async, in flight during S^T AND PV
      }
      half8 ak0 = *(const half8*)&Ks[buf][(w * 16 + l15) * 64 + cs0];
      half8 ak1 = *(const half8*)&Ks[buf][(w * 16 + l15) * 64 + cs1];
      floatx4 sv[4];
#pragma unroll
      for (int nt = 0; nt < 4; ++nt) {
        sv[nt] = __builtin_amdgcn_mfma_f32_16x16x32_f16(ak0, bq[nt][0],
                                                        (floatx4){0.f, 0.f, 0.f, 0.f}, 0, 0, 0);
        sv[nt] = __builtin_amdgcn_mfma_f32_16x16x32_f16(ak1, bq[nt][1], sv[nt], 0, 0, 0);
      }
      const bool diag = (jt == ntile - 1);
#pragma unroll
      for (int nt = 0; nt < 4; ++nt) {
        half4v phv;
#pragma unroll
        for (int r = 0; r < 4; ++r) {
          float p = __expf(sv[nt][r] * 0.125f);
          if (diag) {
            p = (w * 16 + q8 * 4 + r <= nt * 16 + l15) ? p : 0.f;
          }
          lsum[nt] += p;
          phv[r] = (_Float16)p;
        }
        *(half4v*)&Ps[(nt * 16 + l15) * 72 + w * 16 + q8 * 4] = phv;
      }
      // barrier A: P visible (LDS only); K/V prefetch vmem stays in flight
      asm volatile("s_waitcnt lgkmcnt(0)" ::: "memory");
      __builtin_amdgcn_s_barrier();
      asm volatile("" ::: "memory");
      half8 ap0 = *(const half8*)&Ps[(w * 16 + l15) * 72 + q8 * 8];
      half8 ap1 = *(const half8*)&Ps[(w * 16 + l15) * 72 + 32 + q8 * 8];
#pragma unroll
      for (int ntd = 0; ntd < 4; ++ntd) {
        half8 bv0 = *(const half8*)&Vs[buf][(ntd * 16 + l15) * 64 + cs0];
        half8 bv1 = *(const half8*)&Vs[buf][(ntd * 16 + l15) * 64 + cs1];
        acc[ntd] = __builtin_amdgcn_mfma_f32_16x16x32_f16(ap0, bv0, acc[ntd], 0, 0, 0);
        acc[ntd] = __builtin_amdgcn_mfma_f32_16x16x32_f16(ap1, bv1, acc[ntd], 0, 0, 0);
      }
      __syncthreads();  // barrier B: readers done; prefetch drained
    }

#pragma unroll
    for (int nt = 0; nt < 4; ++nt) {
      lsum[nt] += __shfl_xor(lsum[nt], 16);
      lsum[nt] += __shfl_xor(lsum[nt], 32);
      if (q8 == 0) Lpart[w][nt * 16 + l15] = lsum[nt];
    }
    __syncthreads();
    const int b = bh >> 4, h = bh & 15;
#pragma unroll
    for (int r = 0; r < 4; ++r) {
      int qr = w * 16 + q8 * 4 + r;
      float inv = 1.0f / (Lpart[0][qr] + Lpart[1][qr] + Lpart[2][qr] + Lpart[3][qr]);
      int tg = qtile * 64 + qr;
      _Float16* op = ctx + ((size_t)(b * SEQT + tg)) * DMODEL + h * HDIM;
#pragma unroll
      for (int ntd = 0; ntd < 4; ++ntd)
        op[ntd * 16 + l15] = (_Float16)(acc[ntd][r] * inv);
    }
  }
}

// ---------------------------------------------------------------------------
// Host launch. Workspace layout (88 MB, aliased over the timeline):
//  [0,24M)   wt      : transposed f16 weights (persistent)
//  [24,32M)  h16     : LN1 out -> reused as ctx16 after QKV GEMM reads it
//  [32,56M)  q,k,vt  : f16; q,k [B,H,T,HD], v transposed [B,H,HD,T]
//                      -> [32,48M) reused as x1 (fp32), [48,56M) as h2 (f16)
//  [56,88M)  mid16   : f16 [4096,4096]
// ---------------------------------------------------------------------------
extern "C" void kernel_launch(void* const* d_in, const int* in_sizes, int n_in,
                              void* d_out, int out_size, void* d_ws, size_t ws_size,
                              hipStream_t stream) {
  (void)in_sizes; (void)n_in; (void)out_size; (void)ws_size;
  const float* x    = (const float*)d_in[0];
  const float* ln1g = (const float*)d_in[1];
  const float* ln1b = (const float*)d_in[2];
  const float* Wq   = (const float*)d_in[3];
  const float* bq   = (const float*)d_in[4];
  const float* Wk   = (const float*)d_in[5];
  const float* bk   = (const float*)d_in[6];
  const float* Wv   = (const float*)d_in[7];
  const float* bv   = (const float*)d_in[8];
  const float* Wo   = (const float*)d_in[9];
  const float* bo   = (const float*)d_in[10];
  const float* ln2g = (const float*)d_in[11];
  const float* ln2b = (const float*)d_in[12];
  const float* W1   = (const float*)d_in[13];
  const float* b1   = (const float*)d_in[14];
  const float* W2   = (const float*)d_in[15];
  const float* b2   = (const float*)d_in[16];
  float* out = (float*)d_out;

  char* ws = (char*)d_ws;
  _Float16* wt    = (_Float16*)(ws);
  _Float16* h16   = (_Float16*)(ws + ((size_t)24 << 20));
  _Float16* qkv   = (_Float16*)(ws + ((size_t)32 << 20));
  _Float16* ctx16 = (_Float16*)(ws + ((size_t)24 << 20));  // reuse h16
  float*    x1    = (float*)   (ws + ((size_t)32 << 20));  // reuse q,k
  _Float16* h2    = (_Float16*)(ws + ((size_t)48 << 20));  // reuse vt
  _Float16* mid   = (_Float16*)(ws + ((size_t)56 << 20));

  const size_t QKV1 = (size_t)NTOK * DMODEL;  // 4M elements per matrix

  prep_kernel<<<7168, 256, 0, stream>>>(x, ln1g, ln1b, h16,
                                        Wq, Wk, Wv, Wo, W1, W2, wt);
  // QKV: gemmw OUTMODE2, grid (32, 48) = 1536 blocks, 3 blk/CU
  gemmw_kernel<2><<<dim3(32, 48), 256, 0, stream>>>(
      h16, wt, 1024, bq, bk, bv, nullptr, nullptr, qkv);
  attn_kernel<<<dim3(16, 32), 256, 0, stream>>>(
      qkv, qkv + QKV1, qkv + 2 * QKV1, ctx16);
  // Wo: gemmw OUTMODE0
  gemmw_kernel<0><<<dim3(32, 16), 256, 0, stream>>>(
      ctx16, wt + (size_t)3 * 1024 * 1024, 1024, bo, nullptr, nullptr, x, x1, nullptr);
  ln_kernel<<<NTOK, 256, 0, stream>>>(x1, ln2g, ln2b, h2);
  // W1: gemmw OUTMODE1, grid (32, 64) = 2048 blocks, 3 blk/CU
  gemmw_kernel<1><<<dim3(32, 64), 256, 0, stream>>>(
      h2, wt + (size_t)4 * 1024 * 1024, 1024, b1, nullptr, nullptr, nullptr,
      nullptr, mid);
  // W2: gemmw OUTMODE0
  gemmw_kernel<0><<<dim3(32, 16), 256, 0, stream>>>(
      mid, wt + (size_t)8 * 1024 * 1024, 4096, b2, nullptr, nullptr, x1, out, nullptr);
}